// Round 5
// baseline (64194.226 us; speedup 1.0000x reference)
//
#include <hip/hip_runtime.h>

// LSTM B=512, T=512, H=256 — pair-split design.
// 64 blocks x 512 thr. Pair (2p,2p+1): both own batches [16p,16p+16); block
// with hh=bid&1 owns h-range [hh*128, hh*128+128) and the matching 512 gate
// rows of W_hh (256 KB fp16) ENTIRELY in registers (128 VGPR/lane, unified file).
// Per step: compute own h-half; exchange halves with partner via agent-scope
// (sc1, Infinity-Cache coherent) u64 atomics + flag handshake; h also kept in
// LDS (double-buffered) for own-half B-fragments.
// MFMA f32_16x16x32_f16 with W as A-operand, h as B-operand:
//   A[m=l16][k=quad*8+j] = W'[gate-row(m)][k],  B[k=quad*8+j][n=l16] = h[b=n][k]
//   D[m=quad*4+r][n=l16] -> lane owns (gate-rows hl=w*16+quad*4+r, batch b=l16).
// Weights prescaled by -log2e (i,f,o) / +2log2e (g).

typedef _Float16 half8 __attribute__((ext_vector_type(8)));
typedef float f32x4 __attribute__((ext_vector_type(4)));

constexpr int kT = 512;
constexpr float kLog2e = 1.44269504088896340736f;

#define AT_LD(p)    __hip_atomic_load((p), __ATOMIC_RELAXED, __HIP_MEMORY_SCOPE_AGENT)
#define AT_ST(p, v) __hip_atomic_store((p), (v), __ATOMIC_RELAXED, __HIP_MEMORY_SCOPE_AGENT)

// ws byte layout:
//   [0,       524288): weight fragments (fp16), frag f=hh*256+w*32+g*8+kt at wf8[f*64+lane]
//   [524288, 1048576): gbuf: tile(bid,par) at +(bid*2+par)*4096, [b][hl] 16x128 fp16
//   [1048576,1048832): flags, int[64]
//   [1048832,1052928): partials, float[64][16]
__global__ void prep_weights(const float* __restrict__ W_hh, _Float16* __restrict__ ws)
{
    int gid = blockIdx.x * blockDim.x + threadIdx.x;  // 0..32767, one half8 each
    int lane = gid & 63;
    int f = gid >> 6;
    int kt = f & 7, g = (f >> 3) & 3, w = (f >> 5) & 7, hh = (f >> 8) & 1;
    int R = g * 256 + hh * 128 + w * 16 + (lane & 15);
    int k = kt * 32 + (lane >> 4) * 8;
    float s = (g == 2) ? 2.0f * kLog2e : -kLog2e;
    const float* src = W_hh + R * 256 + k;
    half8 v;
    #pragma unroll
    for (int j = 0; j < 8; ++j) v[j] = (_Float16)(src[j] * s);
    reinterpret_cast<half8*>(ws)[gid] = v;
}

__global__ __launch_bounds__(512, 2)
void lstm_main(const float* __restrict__ ts,
               const float* __restrict__ W_ih,
               const float* __restrict__ b_ih,
               const float* __restrict__ b_hh,
               const float* __restrict__ W_out,
               const float* __restrict__ b_out,
               _Float16* __restrict__ wsbase,
               int* __restrict__ flags,
               float* __restrict__ pbuf,
               float* __restrict__ out)
{
    __shared__ __align__(16) _Float16 h_lds[2][16][136]; // [par][b][hl], row 272 B (16B-mult)
    __shared__ float red[8][16];

    const int tid  = threadIdx.x;
    const int w    = tid >> 6;
    const int lane = tid & 63;
    const int l16  = lane & 15;
    const int quad = lane >> 4;
    const int bid  = blockIdx.x;
    const int hh   = bid & 1;
    const int partner = bid ^ 1;
    const int b0   = (bid >> 1) * 16;
    const int hs   = hh * 128;

    const half8* wf8 = reinterpret_cast<const half8*>(wsbase);
    _Float16* gb = wsbase + 262144;  // halves
    _Float16* myt[2] = { gb + (bid * 2 + 0) * 2048, gb + (bid * 2 + 1) * 2048 };
    _Float16* pat[2] = { gb + (partner * 2 + 0) * 2048, gb + (partner * 2 + 1) * 2048 };

    // ---- weights -> registers (compiler places in unified VGPR/AGPR file) ----
    half8 wreg[4][8];
    #pragma unroll
    for (int g = 0; g < 4; ++g)
        #pragma unroll
        for (int kt = 0; kt < 8; ++kt)
            wreg[g][kt] = wf8[(hh * 256 + w * 32 + g * 8 + kt) * 64 + lane];

    // per-(g,r) scalars for gate rows R = g*256 + hs + w*16 + quad*4 + r (prescaled)
    float wih[4][4], bias[4][4];
    #pragma unroll
    for (int g = 0; g < 4; ++g) {
        float s = (g == 2) ? 2.0f * kLog2e : -kLog2e;
        #pragma unroll
        for (int r = 0; r < 4; ++r) {
            int R = g * 256 + hs + w * 16 + quad * 4 + r;
            wih[g][r]  = W_ih[R] * s;
            bias[g][r] = (b_ih[R] + b_hh[R]) * s;
        }
    }

    // zero h_lds parity 1 (t=0 reads it)
    for (int i = tid; i < 16 * 136; i += 512)
        (&h_lds[1][0][0])[i] = (_Float16)0.0f;

    float cst[4] = {0.f, 0.f, 0.f, 0.f};
    float oacc = 0.f;

    __syncthreads();

    for (int t = 0; t < kT; ++t) {
        const int rp = (t + 1) & 1;   // parity holding h_{t-1}
        const int wp = t & 1;

        // wait for partner's h_{t-1}
        if (t > 0) {
            while (__hip_atomic_load(&flags[partner], __ATOMIC_ACQUIRE,
                                     __HIP_MEMORY_SCOPE_AGENT) < t)
                __builtin_amdgcn_s_sleep(1);
        }

        half8 hf[8];
        // partner half first (long-latency agent loads, issued early)
        {
            const _Float16* pt = pat[rp];
            #pragma unroll
            for (int kk = 0; kk < 4; ++kk) {
                int kt = (1 - hh) * 4 + kk;
                int klocal = kk * 32 + quad * 8;
                const unsigned long long* p =
                    (const unsigned long long*)(pt + l16 * 128 + klocal);
                union { unsigned long long u[2]; half8 h; } cv;
                cv.u[0] = AT_LD((unsigned long long*)p);
                cv.u[1] = AT_LD((unsigned long long*)(p + 1));
                hf[kt] = cv.h;
            }
        }
        // own half from LDS
        #pragma unroll
        for (int kk = 0; kk < 4; ++kk) {
            int kt = hh * 4 + kk;
            int klocal = kk * 32 + quad * 8;
            hf[kt] = *reinterpret_cast<const half8*>(&h_lds[rp][l16][klocal]);
        }

        float tsv = ts[(b0 + l16) * kT + t];
        f32x4 wo = *reinterpret_cast<const f32x4*>(&W_out[t * 256 + hs + w * 16 + quad * 4]);

        f32x4 acc[4];
        #pragma unroll
        for (int g = 0; g < 4; ++g) {
            f32x4 z = {0.f, 0.f, 0.f, 0.f};
            acc[g] = z;
        }
        #pragma unroll
        for (int kk = 0; kk < 8; ++kk) {
            int kt = (kk + hh * 4) & 7;    // own slices first
            #pragma unroll
            for (int g = 0; g < 4; ++g)
                acc[g] = __builtin_amdgcn_mfma_f32_16x16x32_f16(wreg[g][kt], hf[kt], acc[g], 0, 0, 0);
        }

        // nonlinearity: lane owns (hl = w*16+quad*4+r, b = l16), gates prescaled
        union { unsigned long long u; _Float16 h[4]; } hpack;
        #pragma unroll
        for (int r = 0; r < 4; ++r) {
            float gi = acc[0][r] + (tsv * wih[0][r] + bias[0][r]);
            float gf = acc[1][r] + (tsv * wih[1][r] + bias[1][r]);
            float gg = acc[2][r] + (tsv * wih[2][r] + bias[2][r]);
            float go = acc[3][r] + (tsv * wih[3][r] + bias[3][r]);
            float I = __builtin_amdgcn_rcpf(1.0f + __builtin_amdgcn_exp2f(gi));
            float F = __builtin_amdgcn_rcpf(1.0f + __builtin_amdgcn_exp2f(gf));
            float G = 1.0f - 2.0f * __builtin_amdgcn_rcpf(1.0f + __builtin_amdgcn_exp2f(gg));
            float O = __builtin_amdgcn_rcpf(1.0f + __builtin_amdgcn_exp2f(go));
            float c = F * cst[r] + I * G;
            cst[r] = c;
            float tc = 1.0f - 2.0f * __builtin_amdgcn_rcpf(
                           1.0f + __builtin_amdgcn_exp2f(2.0f * kLog2e * c));
            float hv = O * tc;
            oacc += hv * wo[r];
            hpack.h[r] = (_Float16)hv;
        }
        // own-use copy (LDS) + partner-visible copy (agent store to IF)
        *reinterpret_cast<unsigned long long*>(&h_lds[wp][l16][w * 16 + quad * 4]) = hpack.u;
        AT_ST((unsigned long long*)(myt[wp] + l16 * 128 + w * 16 + quad * 4), hpack.u);

        __syncthreads();   // LDS visible for t+1; all waves' agent stores drained (vmcnt)
        if (tid == 0)
            __hip_atomic_store(&flags[bid], t + 1, __ATOMIC_RELEASE, __HIP_MEMORY_SCOPE_AGENT);
    }

    // ---- output: sum oacc over quads (same l16), then waves, then pair ----
    float v = oacc;
    v += __shfl_xor(v, 16, 64);
    v += __shfl_xor(v, 32, 64);
    if (quad == 0) red[w][l16] = v;
    __syncthreads();
    float s = 0.f;
    if (tid < 16) {
        #pragma unroll
        for (int ww = 0; ww < 8; ++ww) s += red[ww][tid];
        AT_ST(&pbuf[bid * 16 + tid], s);
    }
    __syncthreads();   // drain partial stores
    if (tid == 0)
        __hip_atomic_store(&flags[bid], kT + 1, __ATOMIC_RELEASE, __HIP_MEMORY_SCOPE_AGENT);
    if (hh == 0 && tid < 16) {
        while (__hip_atomic_load(&flags[partner], __ATOMIC_ACQUIRE,
                                 __HIP_MEMORY_SCOPE_AGENT) < kT + 1)
            __builtin_amdgcn_s_sleep(1);
        float theirs = AT_LD(&pbuf[partner * 16 + tid]);
        out[b0 + tid] = b_out[0] + s + theirs;
    }
}

extern "C" void kernel_launch(void* const* d_in, const int* in_sizes, int n_in,
                              void* d_out, int out_size, void* d_ws, size_t ws_size,
                              hipStream_t stream) {
    const float* ts    = (const float*)d_in[0];
    const float* W_ih  = (const float*)d_in[1];
    const float* W_hh  = (const float*)d_in[2];
    const float* b_ih  = (const float*)d_in[3];
    const float* b_hh  = (const float*)d_in[4];
    const float* W_out = (const float*)d_in[5];
    const float* b_out = (const float*)d_in[6];

    char* wsb = (char*)d_ws;
    _Float16* wfrag = (_Float16*)wsb;
    int*   flags = (int*)(wsb + 1048576);
    float* pbuf  = (float*)(wsb + 1048832);

    // zero gbuf + flags + partials (graph-capture-safe)
    hipMemsetAsync(wsb + 524288, 0, 528640, stream);
    prep_weights<<<128, 256, 0, stream>>>(W_hh, wfrag);
    lstm_main<<<64, 512, 0, stream>>>(ts, W_ih, b_ih, b_hh, W_out, b_out,
                                      wfrag, flags, pbuf, (float*)d_out);
}

// Round 6
// 2660.979 us; speedup vs baseline: 24.1243x; 24.1243x over previous
//
#include <hip/hip_runtime.h>

// LSTM B=512, T=512, H=256. Round 6: pinned-register weight tier.
// Lesson from r4/r5: the compiler NEVER keeps big weight arrays live across the
// t-loop — it remats (reload from L2/step, r4) or spills (r5 catastrophe).
// Fix: load fragments, then asm volatile("" : "+v") — opaque, non-remat.
// 32 blocks x 256 thr (4 waves, 1/SIMD -> 512-reg budget). Block owns 16 batches;
// wave w owns h-cols [64w,64w+64). Tiers per wave (by K-slice kt):
//   kt 0..3 reg (256 regs/lane pinned) | kt 4..5 LDS (128 KB) | kt 6..7 L2 stream.
// MFMA f32_16x16x32_f16: A=h (m=batch=lane&15), B=weights (n=col=lane&15),
// D[m=quad*4+r][n]; weights prescaled by -log2e (i,f,o) / +2log2e (g).
// t16 = g*4 + e*2 + cg; col = w*64 + cg*32 + 2*l16 + e; R = g*256 + col.

typedef _Float16 half8 __attribute__((ext_vector_type(8)));
typedef float f32x4 __attribute__((ext_vector_type(4)));
typedef float f32x2 __attribute__((ext_vector_type(2)));

constexpr int kT = 512;
constexpr int kHP = 280;   // h_lds row stride in halves: 560B -> 2-way banks (free)
constexpr float kLog2e = 1.44269504088896340736f;

// frag table (half8 index = f*64 + lane):
//   REG : f =       w*64 + t16*4 + kt       (kt 0..3)  f in [0,256)
//   LDSW: f = 256 + w*32 + t16*2 + (kt-4)   (kt 4..5)  f in [256,384)
//   STRM: f = 384 + w*32 + t16*2 + (kt-6)   (kt 6..7)  f in [384,512)
__global__ void prep_weights(const float* __restrict__ W_hh, _Float16* __restrict__ ws)
{
    int gid = blockIdx.x * blockDim.x + threadIdx.x;   // 0..32767
    int lane = gid & 63;
    int f = gid >> 6;
    int w, t16, kt;
    if (f < 256)      { w = f >> 6;            int rm = f & 63; t16 = rm >> 2; kt = rm & 3; }
    else if (f < 384) { int q = f - 256; w = q >> 5; int rm = q & 31; t16 = rm >> 1; kt = 4 + (rm & 1); }
    else              { int q = f - 384; w = q >> 5; int rm = q & 31; t16 = rm >> 1; kt = 6 + (rm & 1); }
    int g = t16 >> 2, e = (t16 >> 1) & 1, cg = t16 & 1;
    int R = g * 256 + w * 64 + cg * 32 + 2 * (lane & 15) + e;
    int k = kt * 32 + (lane >> 4) * 8;
    float s = (g == 2) ? 2.0f * kLog2e : -kLog2e;
    const float* src = W_hh + R * 256 + k;
    half8 v;
    #pragma unroll
    for (int j = 0; j < 8; ++j) v[j] = (_Float16)(src[j] * s);
    reinterpret_cast<half8*>(ws)[gid] = v;
}

__device__ __forceinline__ f32x4 mfma16(half8 a, half8 b, f32x4 c) {
    return __builtin_amdgcn_mfma_f32_16x16x32_f16(a, b, c, 0, 0, 0);
}
__device__ __forceinline__ f32x2 unpack2(unsigned int u) {
    union { unsigned int u; _Float16 h[2]; } cv; cv.u = u;
    f32x2 r; r.x = (float)cv.h[0]; r.y = (float)cv.h[1]; return r;
}

__global__ __launch_bounds__(256, 1)
void lstm_main(const float* __restrict__ ts,
               const float* __restrict__ W_ih,
               const float* __restrict__ b_ih,
               const float* __restrict__ b_hh,
               const float* __restrict__ W_out,
               const float* __restrict__ b_out,
               const _Float16* __restrict__ wfrag,
               float* __restrict__ out)
{
    __shared__ __align__(16) _Float16 wlds[65536];        // 128 KB (kt 4..5)
    __shared__ __align__(16) _Float16 h_lds[2][16][kHP];  // ~17.9 KB
    __shared__ float red[4][16];

    const int tid  = threadIdx.x;
    const int w    = tid >> 6;       // wave 0..3
    const int lane = tid & 63;
    const int l16  = lane & 15;
    const int quad = lane >> 4;
    const int b0   = blockIdx.x * 16;

    const half8* wf8 = reinterpret_cast<const half8*>(wfrag);
    half8* wlds8 = reinterpret_cast<half8*>(wlds);

    // stage LDS weight tier (one-time)
    for (int i = tid; i < 8192; i += 256) wlds8[i] = wf8[16384 + i];
    // zero h parity-1 buffer (t=0 reads it)
    for (int i = tid; i < 16 * kHP; i += 256)
        (&h_lds[1][0][0])[i] = (_Float16)0.0f;

    // ---- PINNED register tier: 64 frags x 4 dwords = 256 VGPRs/lane ----
    unsigned int wr[64][4];
    {
        const uint4* wsrc = reinterpret_cast<const uint4*>(wfrag);
        #pragma unroll
        for (int i = 0; i < 64; ++i) {
            uint4 v = wsrc[(w * 64 + i) * 64 + lane];
            wr[i][0] = v.x; wr[i][1] = v.y; wr[i][2] = v.z; wr[i][3] = v.w;
            asm volatile("" : "+v"(wr[i][0]), "+v"(wr[i][1]), "+v"(wr[i][2]), "+v"(wr[i][3]));
        }
    }

    // per-gate-col scalars, prescaled, packed fp16 (wih, bias)
    unsigned int wb16[16];
    #pragma unroll
    for (int t16 = 0; t16 < 16; ++t16) {
        int g = t16 >> 2, e = (t16 >> 1) & 1, cg = t16 & 1;
        int R = g * 256 + w * 64 + cg * 32 + 2 * l16 + e;
        float s = (g == 2) ? 2.0f * kLog2e : -kLog2e;
        union { unsigned int u; _Float16 h[2]; } cv;
        cv.h[0] = (_Float16)(W_ih[R] * s);
        cv.h[1] = (_Float16)((b_ih[R] + b_hh[R]) * s);
        wb16[t16] = cv.u;
    }

    const half8* sps = wf8 + 24576 + w * 2048 + lane;   // STRM base (f=384)

    float cst[16];
    #pragma unroll
    for (int i = 0; i < 16; ++i) cst[i] = 0.0f;
    float oacc[4] = {0.f, 0.f, 0.f, 0.f};

    __syncthreads();

    for (int t = 0; t < kT; ++t) {
        const int rp = (t + 1) & 1, wp = t & 1;

        // A fragments (h) from LDS
        half8 a[8];
        #pragma unroll
        for (int kt = 0; kt < 8; ++kt)
            a[kt] = *reinterpret_cast<const half8*>(&h_lds[rp][l16][kt * 32 + quad * 8]);

        float tsv[4];
        #pragma unroll
        for (int r = 0; r < 4; ++r) tsv[r] = ts[(b0 + quad * 4 + r) * kT + t];

        #pragma unroll
        for (int cg = 0; cg < 2; ++cg) {
            f32x2 wo = *reinterpret_cast<const f32x2*>(&W_out[t * 256 + w * 64 + cg * 32 + 2 * l16]);
            float hv0[4];
            #pragma unroll
            for (int e = 0; e < 2; ++e) {
                // stream tier: issue all 8 loads for this (cg,e) early
                half8 s6[4], s7[4];
                #pragma unroll
                for (int g = 0; g < 4; ++g) {
                    int t16 = g * 4 + e * 2 + cg;
                    s6[g] = sps[(t16 * 2 + 0) * 64];
                    s7[g] = sps[(t16 * 2 + 1) * 64];
                }
                f32x4 gacc[4];
                #pragma unroll
                for (int g = 0; g < 4; ++g) { f32x4 z = {0.f,0.f,0.f,0.f}; gacc[g] = z; }
                // reg tier, kt-outer => 4 independent MFMA chains
                #pragma unroll
                for (int kt = 0; kt < 4; ++kt)
                    #pragma unroll
                    for (int g = 0; g < 4; ++g) {
                        int fi = (g * 4 + e * 2 + cg) * 4 + kt;
                        half8 wv = __builtin_bit_cast(half8,
                            make_uint4(wr[fi][0], wr[fi][1], wr[fi][2], wr[fi][3]));
                        gacc[g] = mfma16(a[kt], wv, gacc[g]);
                    }
                // LDS tier
                #pragma unroll
                for (int kk = 0; kk < 2; ++kk)
                    #pragma unroll
                    for (int g = 0; g < 4; ++g) {
                        int t16 = g * 4 + e * 2 + cg;
                        half8 lw = wlds8[(w * 32 + t16 * 2 + kk) * 64 + lane];
                        gacc[g] = mfma16(a[4 + kk], lw, gacc[g]);
                    }
                // stream tier
                #pragma unroll
                for (int g = 0; g < 4; ++g) gacc[g] = mfma16(a[6], s6[g], gacc[g]);
                #pragma unroll
                for (int g = 0; g < 4; ++g) gacc[g] = mfma16(a[7], s7[g], gacc[g]);

                // nonlinearity for (cg,e): lane owns batch=quad*4+r, col=w*64+cg*32+2*l16+e
                f32x2 ib[4];
                #pragma unroll
                for (int g = 0; g < 4; ++g) ib[g] = unpack2(wb16[g * 4 + e * 2 + cg]);
                #pragma unroll
                for (int r = 0; r < 4; ++r) {
                    float gi = gacc[0][r] + (tsv[r] * ib[0].x + ib[0].y);
                    float gf = gacc[1][r] + (tsv[r] * ib[1].x + ib[1].y);
                    float gg = gacc[2][r] + (tsv[r] * ib[2].x + ib[2].y);
                    float go = gacc[3][r] + (tsv[r] * ib[3].x + ib[3].y);
                    float I = __builtin_amdgcn_rcpf(1.0f + __builtin_amdgcn_exp2f(gi));
                    float F = __builtin_amdgcn_rcpf(1.0f + __builtin_amdgcn_exp2f(gf));
                    float G = 1.0f - 2.0f * __builtin_amdgcn_rcpf(1.0f + __builtin_amdgcn_exp2f(gg));
                    float O = __builtin_amdgcn_rcpf(1.0f + __builtin_amdgcn_exp2f(go));
                    int ci = (cg * 2 + e) * 4 + r;
                    float c = F * cst[ci] + I * G;
                    cst[ci] = c;
                    float tc = 1.0f - 2.0f * __builtin_amdgcn_rcpf(
                                   1.0f + __builtin_amdgcn_exp2f(2.0f * kLog2e * c));
                    float hv = O * tc;
                    oacc[r] += hv * (e ? wo.y : wo.x);
                    if (e == 0) hv0[r] = hv;
                    else {
                        union { unsigned int u; _Float16 h[2]; } hp;
                        hp.h[0] = (_Float16)hv0[r];
                        hp.h[1] = (_Float16)hv;
                        *reinterpret_cast<unsigned int*>(
                            &h_lds[wp][quad * 4 + r][w * 64 + cg * 32 + 2 * l16]) = hp.u;
                    }
                }
            }
        }
        __syncthreads();
    }

    // reduce oacc over l16 lanes, then waves
    #pragma unroll
    for (int r = 0; r < 4; ++r) {
        float v = oacc[r];
        v += __shfl_xor(v, 1, 64);
        v += __shfl_xor(v, 2, 64);
        v += __shfl_xor(v, 4, 64);
        v += __shfl_xor(v, 8, 64);
        oacc[r] = v;
    }
    if (l16 == 0) {
        #pragma unroll
        for (int r = 0; r < 4; ++r) red[w][quad * 4 + r] = oacc[r];
    }
    __syncthreads();
    if (tid < 16) {
        float s = b_out[0];
        #pragma unroll
        for (int ww = 0; ww < 4; ++ww) s += red[ww][tid];
        out[b0 + tid] = s;
    }
}

extern "C" void kernel_launch(void* const* d_in, const int* in_sizes, int n_in,
                              void* d_out, int out_size, void* d_ws, size_t ws_size,
                              hipStream_t stream) {
    const float* ts    = (const float*)d_in[0];
    const float* W_ih  = (const float*)d_in[1];
    const float* W_hh  = (const float*)d_in[2];
    const float* b_ih  = (const float*)d_in[3];
    const float* b_hh  = (const float*)d_in[4];
    const float* W_out = (const float*)d_in[5];
    const float* b_out = (const float*)d_in[6];
    _Float16* wfrag = (_Float16*)d_ws;   // 512 KB of fragments

    prep_weights<<<128, 256, 0, stream>>>(W_hh, wfrag);
    lstm_main<<<32, 256, 0, stream>>>(ts, W_ih, b_ih, b_hh, W_out, b_out,
                                      wfrag, (float*)d_out);
}

// Round 7
// 1649.095 us; speedup vs baseline: 38.9269x; 1.6136x over previous
//
#include <hip/hip_runtime.h>

// LSTM B=512, T=512, H=256. Round 7 = r4 structure + r6's proven asm-pin.
// 32 blocks x 512 thr (8 waves, 2/SIMD => 256-reg budget, real TLP).
// Wave w owns 32 gate-cols (nt=g*2+e tiles); per-wave K-slices (kt):
//   kt 0..3 -> PINNED registers (128 VGPR/lane; asm volatile keeps them live —
//              without the pin the compiler remats from L2 every step, r4's 2x loss)
//   kt 4..5 -> LDS (128 KB, staged once)
//   kt 6..7 -> streamed from L2 each step (128 KB/CU/step = 2048 cyc straw)
// Inner loop split by e (4 gacc tiles at a time) to hold live regs < 256.
// MFMA f32_16x16x32_f16: A=h[m=batch=l16][k], B=W[k][n=col=l16], D[m=quad*4+r][n].
// Weights prescaled by -log2e (i,f,o) / +2log2e (g) => nonlinearity is exp2-only.

typedef _Float16 half8 __attribute__((ext_vector_type(8)));
typedef float f32x4 __attribute__((ext_vector_type(4)));
typedef float f32x2 __attribute__((ext_vector_type(2)));

constexpr int kT = 512;
constexpr int kHP = 272;   // h_lds row stride (halves), 544 B
constexpr float kLog2e = 1.44269504088896340736f;

// ws layout, half8 units (16 B):
//   REG  [0,16384):     f = w*32 + nt*4 + kt          (kt 0..3)
//   LDSW [16384,24576): f = w*16 + nt*2 + (kt-4)      (kt 4..5)
//   STRM [24576,32768): f = w*16 + nt*2 + (kt-6)      (kt 6..7)
// element: nt=g*2+e, col R = g*256 + w*32 + 2*(lane&15) + e, k = kt*32 + (lane>>4)*8 + j
__global__ void prep_weights(const float* __restrict__ W_hh, _Float16* __restrict__ ws)
{
    int gid = blockIdx.x * blockDim.x + threadIdx.x;  // 0..32767
    int lane = gid & 63;
    int w, nt, kt;
    if (gid < 16384) {
        int f = gid >> 6;
        kt = f & 3; nt = (f >> 2) & 7; w = f >> 5;
    } else if (gid < 24576) {
        int f = (gid - 16384) >> 6;
        kt = 4 + (f & 1); nt = (f >> 1) & 7; w = f >> 4;
    } else {
        int f = (gid - 24576) >> 6;
        kt = 6 + (f & 1); nt = (f >> 1) & 7; w = f >> 4;
    }
    int g = nt >> 1, e = nt & 1;
    int r = g * 256 + w * 32 + 2 * (lane & 15) + e;
    int k = kt * 32 + (lane >> 4) * 8;
    float s = (g == 2) ? 2.0f * kLog2e : -kLog2e;
    const float* src = W_hh + r * 256 + k;
    half8 v;
    #pragma unroll
    for (int j = 0; j < 8; ++j) v[j] = (_Float16)(src[j] * s);
    reinterpret_cast<half8*>(ws)[gid] = v;
}

__device__ __forceinline__ f32x4 mfma16(half8 a, half8 b, f32x4 c) {
    return __builtin_amdgcn_mfma_f32_16x16x32_f16(a, b, c, 0, 0, 0);
}
__device__ __forceinline__ f32x2 unpack2(unsigned int u) {
    union { unsigned int u; _Float16 h[2]; } cv; cv.u = u;
    f32x2 r; r.x = (float)cv.h[0]; r.y = (float)cv.h[1]; return r;
}

__global__ __launch_bounds__(512, 2)
void lstm_main(const float* __restrict__ ts,
               const float* __restrict__ W_ih,
               const float* __restrict__ b_ih,
               const float* __restrict__ b_hh,
               const float* __restrict__ W_out,
               const float* __restrict__ b_out,
               const _Float16* __restrict__ wfrag,
               float* __restrict__ out)
{
    __shared__ __align__(16) _Float16 wlds[65536];        // 128 KB (kt 4..5)
    __shared__ __align__(16) _Float16 h_lds[2][16][kHP];  // 17 KB
    __shared__ float red[8][16];

    const int tid  = threadIdx.x;
    const int w    = tid >> 6;       // wave 0..7
    const int lane = tid & 63;
    const int l16  = lane & 15;
    const int quad = lane >> 4;
    const int b0   = blockIdx.x * 16;

    const half8* wf8 = reinterpret_cast<const half8*>(wfrag);
    half8* wlds8 = reinterpret_cast<half8*>(wlds);

    // stage LDS weight tier (one-time)
    for (int i = tid; i < 8192; i += 512) wlds8[i] = wf8[16384 + i];
    // zero h parity-1 buffer (t=0 reads parity 1)
    for (int i = tid; i < 16 * kHP; i += 512)
        (&h_lds[1][0][0])[i] = (_Float16)0.0f;

    // ---- PINNED register tier: 32 frags x 4 dwords = 128 VGPRs/lane ----
    unsigned int wr_[32][4];
    {
        const uint4* wsrc = reinterpret_cast<const uint4*>(wfrag);
        #pragma unroll
        for (int i = 0; i < 32; ++i) {
            uint4 v = wsrc[(w * 32 + i) * 64 + lane];
            wr_[i][0] = v.x; wr_[i][1] = v.y; wr_[i][2] = v.z; wr_[i][3] = v.w;
            asm volatile("" : "+v"(wr_[i][0]), "+v"(wr_[i][1]), "+v"(wr_[i][2]), "+v"(wr_[i][3]));
        }
    }

    // per-col scalars packed fp16 {wih*s, bias*s} (col = w*32 + 2*l16 + e, nt=g*2+e)
    unsigned int wb16[8];
    #pragma unroll
    for (int nt = 0; nt < 8; ++nt) {
        int g = nt >> 1, e = nt & 1;
        int R = g * 256 + w * 32 + 2 * l16 + e;
        float s = (g == 2) ? 2.0f * kLog2e : -kLog2e;
        union { unsigned int u; _Float16 h[2]; } cv;
        cv.h[0] = (_Float16)(W_ih[R] * s);
        cv.h[1] = (_Float16)((b_ih[R] + b_hh[R]) * s);
        wb16[nt] = cv.u;
    }

    const half8* sps = wf8 + 24576 + w * 1024 + lane;   // STRM: frag (nt,j) at sps[(nt*2+j)*64]

    float cst[8] = {0,0,0,0,0,0,0,0};
    float oacc[4] = {0.f, 0.f, 0.f, 0.f};

    __syncthreads();

    for (int t = 0; t < kT; ++t) {
        const int rp = (t + 1) & 1, wp = t & 1;

        // A fragments (h) from LDS
        half8 a[8];
        #pragma unroll
        for (int kt = 0; kt < 8; ++kt)
            a[kt] = *reinterpret_cast<const half8*>(&h_lds[rp][l16][kt * 32 + quad * 8]);

        float tsv[4];
        #pragma unroll
        for (int r = 0; r < 4; ++r) tsv[r] = ts[(b0 + quad * 4 + r) * kT + t];
        f32x2 wo = *reinterpret_cast<const f32x2*>(&W_out[t * 256 + w * 32 + 2 * l16]);

        float hv0[4];
        #pragma unroll
        for (int e = 0; e < 2; ++e) {
            // stream tier loads for this e: nt = g*2+e, kt 6..7 (issued first, consumed last)
            half8 s6[4], s7[4];
            #pragma unroll
            for (int g = 0; g < 4; ++g) {
                int nt = g * 2 + e;
                s6[g] = sps[(nt * 2 + 0) * 64];
                s7[g] = sps[(nt * 2 + 1) * 64];
            }
            f32x4 gacc[4];
            #pragma unroll
            for (int g = 0; g < 4; ++g) { f32x4 z = {0.f,0.f,0.f,0.f}; gacc[g] = z; }
            // reg tier (kt-outer => 4 independent chains)
            #pragma unroll
            for (int kt = 0; kt < 4; ++kt)
                #pragma unroll
                for (int g = 0; g < 4; ++g) {
                    int fi = (g * 2 + e) * 4 + kt;
                    half8 wv = __builtin_bit_cast(half8,
                        make_uint4(wr_[fi][0], wr_[fi][1], wr_[fi][2], wr_[fi][3]));
                    gacc[g] = mfma16(a[kt], wv, gacc[g]);
                }
            // LDS tier
            #pragma unroll
            for (int kk = 0; kk < 2; ++kk)
                #pragma unroll
                for (int g = 0; g < 4; ++g) {
                    int nt = g * 2 + e;
                    half8 lw = wlds8[(w * 16 + nt * 2 + kk) * 64 + lane];
                    gacc[g] = mfma16(a[4 + kk], lw, gacc[g]);
                }
            // stream tier
            #pragma unroll
            for (int g = 0; g < 4; ++g) gacc[g] = mfma16(a[6], s6[g], gacc[g]);
            #pragma unroll
            for (int g = 0; g < 4; ++g) gacc[g] = mfma16(a[7], s7[g], gacc[g]);

            // nonlinearity: lane owns (batch = quad*4+r, col = w*32 + 2*l16 + e)
            f32x2 ib[4];
            #pragma unroll
            for (int g = 0; g < 4; ++g) ib[g] = unpack2(wb16[g * 2 + e]);
            #pragma unroll
            for (int r = 0; r < 4; ++r) {
                float gi = gacc[0][r] + (tsv[r] * ib[0].x + ib[0].y);
                float gf = gacc[1][r] + (tsv[r] * ib[1].x + ib[1].y);
                float gg = gacc[2][r] + (tsv[r] * ib[2].x + ib[2].y);
                float go = gacc[3][r] + (tsv[r] * ib[3].x + ib[3].y);
                float I = __builtin_amdgcn_rcpf(1.0f + __builtin_amdgcn_exp2f(gi));
                float F = __builtin_amdgcn_rcpf(1.0f + __builtin_amdgcn_exp2f(gf));
                float G = 1.0f - 2.0f * __builtin_amdgcn_rcpf(1.0f + __builtin_amdgcn_exp2f(gg));
                float O = __builtin_amdgcn_rcpf(1.0f + __builtin_amdgcn_exp2f(go));
                float c = F * cst[e * 4 + r] + I * G;
                cst[e * 4 + r] = c;
                float tc = 1.0f - 2.0f * __builtin_amdgcn_rcpf(
                               1.0f + __builtin_amdgcn_exp2f(2.0f * kLog2e * c));
                float hv = O * tc;
                oacc[r] += hv * (e ? wo.y : wo.x);
                if (e == 0) hv0[r] = hv;
                else {
                    union { unsigned int u; _Float16 h[2]; } hp;
                    hp.h[0] = (_Float16)hv0[r];
                    hp.h[1] = (_Float16)hv;
                    *reinterpret_cast<unsigned int*>(
                        &h_lds[wp][quad * 4 + r][w * 32 + 2 * l16]) = hp.u;
                }
            }
        }
        __syncthreads();
    }

    // reduce oacc over l16 lanes (cols), then waves
    #pragma unroll
    for (int r = 0; r < 4; ++r) {
        float v = oacc[r];
        v += __shfl_xor(v, 1, 64);
        v += __shfl_xor(v, 2, 64);
        v += __shfl_xor(v, 4, 64);
        v += __shfl_xor(v, 8, 64);
        oacc[r] = v;
    }
    if (l16 == 0) {
        #pragma unroll
        for (int r = 0; r < 4; ++r) red[w][quad * 4 + r] = oacc[r];
    }
    __syncthreads();
    if (tid < 16) {
        float s = b_out[0];
        #pragma unroll
        for (int ww = 0; ww < 8; ++ww) s += red[ww][tid];
        out[b0 + tid] = s;
    }
}

extern "C" void kernel_launch(void* const* d_in, const int* in_sizes, int n_in,
                              void* d_out, int out_size, void* d_ws, size_t ws_size,
                              hipStream_t stream) {
    const float* ts    = (const float*)d_in[0];
    const float* W_ih  = (const float*)d_in[1];
    const float* W_hh  = (const float*)d_in[2];
    const float* b_ih  = (const float*)d_in[3];
    const float* b_hh  = (const float*)d_in[4];
    const float* W_out = (const float*)d_in[5];
    const float* b_out = (const float*)d_in[6];
    _Float16* wfrag = (_Float16*)d_ws;   // 512 KB of fragments

    prep_weights<<<128, 256, 0, stream>>>(W_hh, wfrag);
    lstm_main<<<32, 512, 0, stream>>>(ts, W_ih, b_ih, b_hh, W_out, b_out,
                                      wfrag, (float*)d_out);
}